// Round 5
// baseline (276.520 us; speedup 1.0000x reference)
//
#include <hip/hip_runtime.h>

#define DIN   256
#define HID   8192
#define BATCH 8192
#define TOPK  32
#define BM    64          // rows per sae_enc block
#define HHALF 4096
#define NCH   16          // hid chunks per half (256 latents each)
#define NS1   48          // per-half kept candidates (gkeys interface)
#define MRG   96          // merged candidates per row
#define NS2   48          // exact-rerank count
#define AS_LD 264         // 528 B row stride
#define XF_LD 260
#define CAP   112         // per-row spill cap (mean 57, 7.3 sigma)
#define K2_LD 113         // keys2 stride: odd => conflict-free row broadcast
#define THRM  0.1375f     // 2.2 / 16: threshold = 2.2 * (|x - b_dec| / sqrt(DIN))
#define D1R   8           // rows per sae_rank block
#define D2R   4           // rows per sae_out block
#define GK_OFF ((size_t)4 << 20)   // key buffer offset in ws (after 4MiB wsb)

typedef __bf16 bf16x8 __attribute__((ext_vector_type(8)));
typedef unsigned short u16x8 __attribute__((ext_vector_type(8)));
typedef float f32x4v __attribute__((ext_vector_type(4)));

__device__ __forceinline__ unsigned short f2bf(float f) {
  unsigned x = __builtin_bit_cast(unsigned, f);
  x = x + 0x7fffu + ((x >> 16) & 1u);   // RNE, finite only
  return (unsigned short)(x >> 16);
}

// ---------------- Kernel A: W_enc f32 -> bf16, MFMA-B-fragment layout ----
__global__ __launch_bounds__(512) void wenc_cast(
    const float* __restrict__ Wenc, unsigned short* __restrict__ wsb)
{
  const int g = (int)blockIdx.x * 512 + (int)threadIdx.x;  // 262144 units
  const int h = g >> 5, u = g & 31, kg = u >> 2, quad = u & 3;
  const float* src = Wenc + (size_t)h * DIN + kg * 32 + quad * 8;
  float4 a = *(const float4*)src;
  float4 b = *(const float4*)(src + 4);
  u16x8 o;
  o[0] = f2bf(a.x); o[1] = f2bf(a.y); o[2] = f2bf(a.z); o[3] = f2bf(a.w);
  o[4] = f2bf(b.x); o[5] = f2bf(b.y); o[6] = f2bf(b.z); o[7] = f2bf(b.w);
  *(u16x8*)(wsb + ((size_t)(((h >> 4) * 8 + kg) * 64 + quad * 16 + (h & 15))) * 8) = o;
}

// ---------------- Kernel A2: out[b,:] = b_dec (decode partials atomicAdd later)
__global__ __launch_bounds__(256) void out_init(
    const float* __restrict__ bdec, float* __restrict__ out)
{
  const int g = (int)blockIdx.x * 256 + (int)threadIdx.x;  // 524288 float4s
  const int r = g >> 6, seg = g & 63;
  *(float4*)(out + (size_t)r * DIN + seg * 4) = *(const float4*)(bdec + seg * 4);
}

// ---------------- Kernel B1: encoder GEMM + threshold spill + top-48 ----
// (unchanged from round 4 -- proven at ~60us, no scratch)
__global__ __launch_bounds__(512) void sae_enc(
    const float* __restrict__ x,    const float* __restrict__ benc,
    const float* __restrict__ bdec, const unsigned short* __restrict__ wsb,
    unsigned* __restrict__ gkeys)
{
  __shared__ __align__(16) unsigned short As[BM][AS_LD];   // 33.8 KB
  __shared__ unsigned keys2[BM][K2_LD];                    // 28.9 KB
  __shared__ int   cnt[BM];
  __shared__ float rthr[BM];

  const int tid  = (int)threadIdx.x;
  const int wave = tid >> 6;
  const int lane = tid & 63;
  const int quad = lane >> 4;
  const int ln15 = lane & 15;
  const int rt   = (int)blockIdx.x >> 1;
  const int hs   = (int)blockIdx.x & 1;
  const int mb   = rt * BM;

  #pragma unroll
  for (int u = 0; u < 2; ++u) {
    const int idx = u * 512 + tid;
    const int r = idx >> 4, seg = idx & 15;
    const float* xs = x + (size_t)(mb + r) * DIN + seg * 16;
    const float* bs = bdec + seg * 16;
    float ss = 0.0f;
    #pragma unroll
    for (int j = 0; j < 4; ++j) {
      float4 xv = *(const float4*)(xs + 4 * j);
      float4 bv = *(const float4*)(bs + 4 * j);
      float dx = xv.x - bv.x, dy = xv.y - bv.y;
      float dz = xv.z - bv.z, dw = xv.w - bv.w;
      ss += dx * dx + dy * dy + dz * dz + dw * dw;
      unsigned short* dst = &As[r][seg * 16 + 4 * j];
      dst[0] = f2bf(dx); dst[1] = f2bf(dy);
      dst[2] = f2bf(dz); dst[3] = f2bf(dw);
    }
    #pragma unroll
    for (int d = 1; d < 16; d <<= 1) ss += __shfl_xor(ss, d, 16);
    if (seg == 0) { rthr[r] = THRM * sqrtf(ss); cnt[r] = 0; }
  }
  __syncthreads();

  bf16x8 afrag[4][8];
  #pragma unroll
  for (int mt = 0; mt < 4; ++mt)
    #pragma unroll
    for (int gk = 0; gk < 8; ++gk)
      afrag[mt][gk] = *(const bf16x8*)&As[mt * 16 + ln15][gk * 32 + quad * 8];

  float thr[16];
  #pragma unroll
  for (int s = 0; s < 16; ++s) thr[s] = rthr[(s >> 2) * 16 + quad * 4 + (s & 3)];

  for (int c = 0; c < NCH; ++c) {
    const unsigned short* bp =
        wsb + (((size_t)(hs * 256 + c * 16 + wave * 2) * 512) + lane) * 8;
    #pragma unroll
    for (int nt = 0; nt < 2; ++nt) {
      bf16x8 bfrag[8];
      #pragma unroll
      for (int kg = 0; kg < 8; ++kg)
        bfrag[kg] = *(const bf16x8*)(bp + (size_t)nt * 4096 + (size_t)kg * 512);

      const int hcol = hs * HHALF + c * 256 + (wave * 2 + nt) * 16 + ln15;
      const float be = benc[hcol];
      f32x4v acc[4];
      #pragma unroll
      for (int mt = 0; mt < 4; ++mt)
        #pragma unroll
        for (int i = 0; i < 4; ++i) acc[mt][i] = be;

      #pragma unroll
      for (int kg = 0; kg < 8; ++kg)
        #pragma unroll
        for (int mt = 0; mt < 4; ++mt)
          acc[mt] = __builtin_amdgcn_mfma_f32_16x16x32_bf16(
              afrag[mt][kg], bfrag[kg], acc[mt], 0, 0, 0);

      const unsigned idxpart = (unsigned)(8191 - hcol);
      #pragma unroll
      for (int mt = 0; mt < 4; ++mt)
        #pragma unroll
        for (int i = 0; i < 4; ++i) {
          const float v = acc[mt][i];
          if (v > thr[mt * 4 + i]) {
            const int row = mt * 16 + quad * 4 + i;
            const int sl = atomicAdd(&cnt[row], 1);
            if (sl < CAP)
              keys2[row][sl] = ((unsigned)f2bf(v) << 16) | idxpart;
          }
        }
    }
  }
  __syncthreads();

  #pragma unroll
  for (int u = 0; u < 2; ++u) {
    const int row = u * 32 + (tid >> 4), l16 = tid & 15;
    const int n = min(cnt[row], CAP);
    unsigned myk[CAP / 16];
    int rk[CAP / 16];
    #pragma unroll
    for (int j = 0; j < CAP / 16; ++j) {
      const int idx = l16 + 16 * j;
      myk[j] = (idx < n) ? keys2[row][idx] : 0u;
      rk[j] = 0;
    }
    for (int e = 0; e < n; ++e) {
      const unsigned k2 = keys2[row][e];
      #pragma unroll
      for (int j = 0; j < CAP / 16; ++j) rk[j] += (k2 > myk[j]) ? 1 : 0;
    }
    unsigned* gout = gkeys + (size_t)(mb + row) * MRG + hs * NS1;
    #pragma unroll
    for (int j = 0; j < CAP / 16; ++j) {
      const int idx = l16 + 16 * j;
      if (idx < n && rk[j] < NS1) gout[rk[j]] = myk[j];
    }
    if (l16 == 0)
      for (int p = n; p < NS1; ++p) gout[p] = (unsigned)(0x4000 + hs * 64 + p);
  }
}

// ---------------- Kernel C1: merge + half-partitioned exact f64 rerank ----
// grid 2048: rb = blockIdx>>1 (8 rows), hs = blockIdx&1. XCD = blockIdx%8
// => each XCD gathers W_enc rows from ONE 4MB half -> half stays L2-resident
// (the r4 sae_dec thrash: 228MB L2-fill at 2.5 TB/s = ~90% of its 95us).
// Both half-blocks duplicate the cheap key-merge; each reranks only its own
// half's candidates (~24/row) and writes (f32 val, h) u64 pairs into
// gpair[row][merge_rank] -- slots disjoint across halves (each h in exactly
// one half; all 48 slots real since total spills >= 48 at -6.2 sigma).
__global__ __launch_bounds__(256) void sae_rank(
    const float* __restrict__ x,    const float* __restrict__ Wenc,
    const float* __restrict__ benc, const float* __restrict__ bdec,
    const unsigned* __restrict__ gkeys, unsigned long long* __restrict__ gpair)
{
  __shared__ unsigned mk[D1R][MRG];
  __shared__ __align__(16) float xf[D1R][XF_LD];
  __shared__ int ti[D1R][NS2];
  __shared__ unsigned short wq[D1R * NS2];
  __shared__ int nwq;

  const int tid = (int)threadIdx.x;
  const int hs  = (int)blockIdx.x & 1;
  const int rb  = (int)blockIdx.x >> 1;
  const int mb  = rb * D1R;
  const int hlo = hs * HHALF, hhi = hlo + HHALF;

  if (tid == 0) nwq = 0;
  for (int i = tid; i < D1R * MRG; i += 256)
    mk[i / MRG][i % MRG] = gkeys[(size_t)mb * MRG + i];

  for (int i = tid; i < D1R * 64; i += 256) {   // stage exact f32 sae_in
    const int r = i >> 6, seg = i & 63;
    float4 xv = *(const float4*)(x + (size_t)(mb + r) * DIN + seg * 4);
    float4 bv = *(const float4*)(bdec + seg * 4);
    float4 d;
    d.x = xv.x - bv.x; d.y = xv.y - bv.y; d.z = xv.z - bv.z; d.w = xv.w - bv.w;
    *(float4*)&xf[r][seg * 4] = d;
  }
  __syncthreads();

  {  // merge: rank-select top-NS2 of 96 (keys unique); 32 lanes/row
    const int row = tid >> 5, l32 = tid & 31;
    unsigned myk[3];
    int rk[3];
    #pragma unroll
    for (int j = 0; j < 3; ++j) { myk[j] = mk[row][l32 + 32 * j]; rk[j] = 0; }
    for (int e = 0; e < MRG; ++e) {
      const unsigned k2 = mk[row][e];
      #pragma unroll
      for (int j = 0; j < 3; ++j) rk[j] += (k2 > myk[j]) ? 1 : 0;
    }
    #pragma unroll
    for (int j = 0; j < 3; ++j)
      if (rk[j] < NS2) ti[row][rk[j]] = 8191 - (int)(myk[j] & 0xFFFFu);
  }
  __syncthreads();

  // compact own-half (row,cand) tasks
  for (int i = tid; i < D1R * NS2; i += 256) {
    const int row = i / NS2, cand = i - row * NS2;
    const int h = ti[row][cand];
    if (h >= hlo && h < hhi) {
      const int p = atomicAdd(&nwq, 1);
      wq[p] = (unsigned short)((row << 6) | cand);
    } else if (h < 0 && hs == 0) {   // pad slot (statistically never): v=0
      gpair[(size_t)(mb + row) * NS2 + cand] = 0ull;
    }
  }
  __syncthreads();

  // exact f64 rerank of queued tasks; 4 subthreads per task (64-elem dots)
  const int nw4 = nwq * 4;
  for (int t = tid; t < nw4; t += 256) {
    const int task = t >> 2, sub = t & 3;
    const int row = wq[task] >> 6, cand = wq[task] & 63;
    const int h = ti[row][cand];
    const float* wp = Wenc + (size_t)h * DIN + sub * 64;
    const float* xp = &xf[row][sub * 64];
    double a0 = 0.0, a1 = 0.0;
    #pragma unroll
    for (int kk = 0; kk < 16; ++kk) {
      float4 w  = *(const float4*)(wp + 4 * kk);
      float4 xv = *(const float4*)(xp + 4 * kk);
      a0 += (double)xv.x * (double)w.x + (double)xv.y * (double)w.y;
      a1 += (double)xv.z * (double)w.z + (double)xv.w * (double)w.w;
    }
    double accd = a0 + a1;
    accd += __shfl_down(accd, 2, 4);
    accd += __shfl_down(accd, 1, 4);
    if (sub == 0) {
      float ev = (float)accd + benc[h];
      ev = ev > 0.0f ? ev : 0.0f;   // relu before ranking (matches ref)
      gpair[(size_t)(mb + row) * NS2 + cand] =
          ((unsigned long long)__builtin_bit_cast(unsigned, ev) << 32) |
          (unsigned)h;
    }
  }
}

// ---------------- Kernel C2: top-32 select + half-partitioned decode ----
// grid 4096: rb = blockIdx>>1 (4 rows), hs = blockIdx&1 (XCD parity => each
// XCD reads one 4MB W_dec half, L2-resident). Both half-blocks compute the
// identical top-32 (same gpair data, same compare); each accumulates only
// its own half's latents and atomicAdds onto out (pre-filled with b_dec).
__global__ __launch_bounds__(256) void sae_out(
    const float* __restrict__ Wdec, const unsigned long long* __restrict__ gpair,
    float* __restrict__ out)
{
  __shared__ float tv[D2R][NS2];
  __shared__ int   ti2[D2R][NS2];
  __shared__ float sv[D2R][TOPK];
  __shared__ int   si[D2R][TOPK];

  const int tid = (int)threadIdx.x;
  const int hs  = (int)blockIdx.x & 1;
  const int rb  = (int)blockIdx.x >> 1;
  const int mb  = rb * D2R;
  const int hlo = hs * HHALF, hhi = hlo + HHALF;

  for (int i = tid; i < D2R * NS2; i += 256) {
    const unsigned long long p = gpair[(size_t)mb * NS2 + i];
    tv[i / NS2][i % NS2] = __builtin_bit_cast(float, (unsigned)(p >> 32));
    ti2[i / NS2][i % NS2] = (int)(unsigned)(p & 0xFFFFFFFFu);
  }
  __syncthreads();

  // parallel exact top-32 rank-select (value desc, idx asc; ranks unique)
  if (tid < D2R * NS2) {
    const int row = tid / NS2, cand = tid - row * NS2;
    const float v = tv[row][cand];
    const int   h = ti2[row][cand];
    int rk = 0;
    for (int e = 0; e < NS2; ++e) {
      const float v2 = tv[row][e];
      const int   h2 = ti2[row][e];
      rk += (v2 > v || (v2 == v && (unsigned)h2 < (unsigned)h)) ? 1 : 0;
    }
    if (rk < TOPK) { sv[row][rk] = v; si[row][rk] = h; }
  }
  __syncthreads();

  // decode partial: 64 threads/row (r wave-uniform => uniform branches)
  {
    const int r = tid >> 6, d0 = (tid & 63) * 4;
    float o0 = 0.0f, o1 = 0.0f, o2 = 0.0f, o3 = 0.0f;
    for (int s = 0; s < TOPK; ++s) {
      const float v = sv[r][s];
      if (!(v > 0.0f)) break;      // sorted desc; wave-uniform
      const int h = si[r][s];
      if (h >= hlo && h < hhi) {   // wave-uniform
        const float* wp = Wdec + (size_t)h * DIN + d0;
        float4 w = *(const float4*)wp;
        o0 += v * w.x; o1 += v * w.y; o2 += v * w.z; o3 += v * w.w;
      }
    }
    float* op = out + (size_t)(mb + r) * DIN + d0;
    atomicAdd(op + 0, o0);
    atomicAdd(op + 1, o1);
    atomicAdd(op + 2, o2);
    atomicAdd(op + 3, o3);
  }
}

extern "C" void kernel_launch(void* const* d_in, const int* in_sizes, int n_in,
                              void* d_out, int out_size, void* d_ws, size_t ws_size,
                              hipStream_t stream) {
  const float* x    = (const float*)d_in[0];
  const float* Wenc = (const float*)d_in[1];
  const float* benc = (const float*)d_in[2];
  const float* Wdec = (const float*)d_in[3];
  const float* bdec = (const float*)d_in[4];
  float* out = (float*)d_out;
  unsigned short* wsb = (unsigned short*)d_ws;                 // 4 MiB bf16 fragments
  unsigned* gkeys = (unsigned*)((char*)d_ws + GK_OFF);         // 3 MiB keys
  // gpair reuses the wsb region (dead after sae_enc): 8192*48*8B = 3 MiB
  unsigned long long* gpair = (unsigned long long*)d_ws;

  wenc_cast<<<dim3((HID * DIN / 8) / 512), dim3(512), 0, stream>>>(Wenc, wsb);
  out_init<<<dim3(BATCH * DIN / 4 / 256), dim3(256), 0, stream>>>(bdec, out);
  sae_enc<<<dim3(2 * BATCH / BM), dim3(512), 0, stream>>>(x, benc, bdec, wsb, gkeys);
  sae_rank<<<dim3(2 * BATCH / D1R), dim3(256), 0, stream>>>(x, Wenc, benc, bdec, gkeys, gpair);
  sae_out<<<dim3(2 * BATCH / D2R), dim3(256), 0, stream>>>(Wdec, gpair, out);
}

// Round 6
// 269.598 us; speedup vs baseline: 1.0257x; 1.0257x over previous
//
#include <hip/hip_runtime.h>

#define DIN   256
#define HID   8192
#define BATCH 8192
#define TOPK  32
#define BM    64          // rows per sae_enc block
#define HHALF 4096
#define NS1   48          // per-half kept candidates (gkeys interface)
#define MRG   96          // merged candidates per row
#define NS2   48          // exact-rerank count
#define AS_LD 264         // 528 B row stride
#define XF_LD 260
#define CAP   112         // per-row spill cap (mean 57, 7.3 sigma)
#define K2_LD 113         // keys2 stride: odd => conflict-free row broadcast
#define THRM  0.1375f     // 2.2 / 16: threshold = 2.2 * (|x - b_dec| / sqrt(DIN))
#define NST   64          // pipeline steps: 256 tiles/half, 4 tiles/step
#define DBM   4           // rows per sae_dec block
#define DT    256         // sae_dec threads
#define GK_OFF ((size_t)4 << 20)   // key buffer offset in ws (after 4MiB wsb)

typedef __bf16 bf16x8 __attribute__((ext_vector_type(8)));
typedef unsigned short u16x8 __attribute__((ext_vector_type(8)));
typedef float f32x4v __attribute__((ext_vector_type(4)));

__device__ __forceinline__ unsigned short f2bf(float f) {
  unsigned x = __builtin_bit_cast(unsigned, f);
  x = x + 0x7fffu + ((x >> 16) & 1u);   // RNE, finite only
  return (unsigned short)(x >> 16);
}

// async global->LDS, 16B per lane: LDS dest = uniform base + lane*16,
// global src is per-lane (must include lane*16).
__device__ __forceinline__ void gload16(const void* g, void* l) {
  __builtin_amdgcn_global_load_lds(
      (const __attribute__((address_space(1))) unsigned int*)g,
      (__attribute__((address_space(3))) unsigned int*)l, 16, 0, 0);
}

// ---------------- Kernel A: W_enc f32 -> bf16, MFMA-B-fragment layout ----
__global__ __launch_bounds__(512) void wenc_cast(
    const float* __restrict__ Wenc, unsigned short* __restrict__ wsb)
{
  const int g = (int)blockIdx.x * 512 + (int)threadIdx.x;  // 262144 units
  const int h = g >> 5, u = g & 31, kg = u >> 2, quad = u & 3;
  const float* src = Wenc + (size_t)h * DIN + kg * 32 + quad * 8;
  float4 a = *(const float4*)src;
  float4 b = *(const float4*)(src + 4);
  u16x8 o;
  o[0] = f2bf(a.x); o[1] = f2bf(a.y); o[2] = f2bf(a.z); o[3] = f2bf(a.w);
  o[4] = f2bf(b.x); o[5] = f2bf(b.y); o[6] = f2bf(b.z); o[7] = f2bf(b.w);
  *(u16x8*)(wsb + ((size_t)(((h >> 4) * 8 + kg) * 64 + quad * 16 + (h & 15))) * 8) = o;
}

// ---------------- Kernel B1: encoder GEMM + threshold spill + top-48 ----
// BM=64 x 512 threads, grid 256. r5 profile: MfmaUtil 16%, 2 waves/SIMD
// (afrag 128 AGPR + 96 VGPR), ~60% stalled on bfrag L2 latency -> fix with
// an async gload_lds double-buffered slab pipeline (counted vmcnt, raw
// s_barrier) + wave-PAIR tile split so afrag is only [2][8] (64 VGPR):
//   wave = mh*4 + w4: w4 = tile within 4-tile step, mh = row half.
// Steady-state loop's only vmem = my 4 gload_lds => vmcnt(4) is exact.
__global__ __launch_bounds__(512) void sae_enc(
    const float* __restrict__ x,    const float* __restrict__ benc,
    const float* __restrict__ bdec, const unsigned short* __restrict__ wsb,
    unsigned* __restrict__ gkeys)
{
  __shared__ __align__(16) union UA {
    unsigned short As[BM][AS_LD];                       // 33.8 KB (dead after afrag)
    struct { unsigned char Bsl[2][32768]; float benc_l[HHALF]; } p;  // 80 KB
  } ua;
  __shared__ unsigned keys2[BM][K2_LD];                 // 28.9 KB
  __shared__ int   cnt[BM];
  __shared__ float rthr[BM];

  const int tid  = (int)threadIdx.x;
  const int wave = tid >> 6;
  const int lane = tid & 63;
  const int quad = lane >> 4;
  const int ln15 = lane & 15;
  const int w4   = wave & 3;        // tile within step
  const int mh   = wave >> 2;       // row half (0: rows 0-31, 1: rows 32-63)
  const int rt   = (int)blockIdx.x >> 1;
  const int hs   = (int)blockIdx.x & 1;
  const int mb   = rt * BM;

  // ---- stage bf16(x - b_dec) rows into LDS.As + per-row threshold ----
  #pragma unroll
  for (int u = 0; u < 2; ++u) {
    const int idx = u * 512 + tid;
    const int r = idx >> 4, seg = idx & 15;
    const float* xs = x + (size_t)(mb + r) * DIN + seg * 16;
    const float* bs = bdec + seg * 16;
    float ss = 0.0f;
    #pragma unroll
    for (int j = 0; j < 4; ++j) {
      float4 xv = *(const float4*)(xs + 4 * j);
      float4 bv = *(const float4*)(bs + 4 * j);
      float dx = xv.x - bv.x, dy = xv.y - bv.y;
      float dz = xv.z - bv.z, dw = xv.w - bv.w;
      ss += dx * dx + dy * dy + dz * dz + dw * dw;
      unsigned short* dst = &ua.As[r][seg * 16 + 4 * j];
      dst[0] = f2bf(dx); dst[1] = f2bf(dy);
      dst[2] = f2bf(dz); dst[3] = f2bf(dw);
    }
    #pragma unroll
    for (int d = 1; d < 16; d <<= 1) ss += __shfl_xor(ss, d, 16);
    if (seg == 0) { rthr[r] = THRM * sqrtf(ss); cnt[r] = 0; }
  }
  __syncthreads();

  // A-fragments for my 32 rows (verified 16x16x32 layout)
  bf16x8 afrag[2][8];
  #pragma unroll
  for (int mt = 0; mt < 2; ++mt)
    #pragma unroll
    for (int gk = 0; gk < 8; ++gk)
      afrag[mt][gk] = *(const bf16x8*)&ua.As[mh * 32 + mt * 16 + ln15][gk * 32 + quad * 8];

  float thr[8];
  #pragma unroll
  for (int s2 = 0; s2 < 8; ++s2)
    thr[s2] = rthr[mh * 32 + (s2 >> 2) * 16 + quad * 4 + (s2 & 3)];
  __syncthreads();   // As fully read before benc_l/Bsl overlay it

  // stage b_enc half into LDS (keeps steady-loop vmem = gload_lds only)
  {
    const float* bsrc = benc + hs * HHALF + tid * 8;
    float4 b0 = *(const float4*)bsrc;
    float4 b1 = *(const float4*)(bsrc + 4);
    *(float4*)&ua.p.benc_l[tid * 8]     = b0;
    *(float4*)&ua.p.benc_l[tid * 8 + 4] = b1;
  }
  {  // prologue: stage step 0 slab into buf 0
    const char* srcb = (const char*)wsb + (size_t)(hs * 256) * 8192
                       + (size_t)(wave * 4096 + lane * 16);
    char* dstb = (char*)&ua.p.Bsl[0][wave * 4096];
    gload16(srcb,        dstb);
    gload16(srcb + 1024, dstb + 1024);
    gload16(srcb + 2048, dstb + 2048);
    gload16(srcb + 3072, dstb + 3072);
  }
  __syncthreads();   // full drain once: benc_l + buf0 ready

  for (int s = 0; s < NST; ++s) {
    const int cur = s & 1;
    if (s + 1 < NST) {   // stage next slab into other buffer (stays in flight)
      const char* srcb = (const char*)wsb
                         + (size_t)(hs * 256 + (s + 1) * 4) * 8192
                         + (size_t)(wave * 4096 + lane * 16);
      char* dstb = (char*)&ua.p.Bsl[cur ^ 1][wave * 4096];
      gload16(srcb,        dstb);
      gload16(srcb + 1024, dstb + 1024);
      gload16(srcb + 2048, dstb + 2048);
      gload16(srcb + 3072, dstb + 3072);
      asm volatile("s_waitcnt vmcnt(4)" ::: "memory");  // cur's 4 done, next's fly
    } else {
      asm volatile("s_waitcnt vmcnt(0)" ::: "memory");
    }
    __builtin_amdgcn_s_barrier();   // raw: does NOT drain the 4 in-flight loads

    // ---- compute my tile (16 cols) x my 32 rows ----
    const int hwl = (s * 4 + w4) * 16 + ln15;     // within-half column
    const float be = ua.p.benc_l[hwl];
    f32x4v acc[2];
    #pragma unroll
    for (int mt = 0; mt < 2; ++mt)
      #pragma unroll
      for (int i = 0; i < 4; ++i) acc[mt][i] = be;   // b_enc folded into init

    const char* bb = (const char*)&ua.p.Bsl[cur][w4 * 8192] + (size_t)lane * 16;
    #pragma unroll
    for (int kg = 0; kg < 8; ++kg) {
      bf16x8 bfrag = *(const bf16x8*)(bb + kg * 1024);
      acc[0] = __builtin_amdgcn_mfma_f32_16x16x32_bf16(afrag[0][kg], bfrag, acc[0], 0, 0, 0);
      acc[1] = __builtin_amdgcn_mfma_f32_16x16x32_bf16(afrag[1][kg], bfrag, acc[1], 0, 0, 0);
    }

    // epilogue: threshold compare + direct per-row spill (rare)
    const unsigned idxpart = (unsigned)(8191 - (hs * HHALF + hwl));
    #pragma unroll
    for (int mt = 0; mt < 2; ++mt)
      #pragma unroll
      for (int i = 0; i < 4; ++i) {
        const float v = acc[mt][i];
        if (v > thr[mt * 4 + i]) {       // thr>0 => v>thr implies relu(v)=v
          const int row = mh * 32 + mt * 16 + quad * 4 + i;
          const int sl = atomicAdd(&cnt[row], 1);
          if (sl < CAP)
            keys2[row][sl] = ((unsigned)f2bf(v) << 16) | idxpart;
        }
      }
    asm volatile("s_waitcnt lgkmcnt(0)" ::: "memory");
    __builtin_amdgcn_s_barrier();   // all reads of cur done before overwrite
  }
  __syncthreads();

  // rank-select top-NS1 per row (keys unique) -> global key buffer
  #pragma unroll
  for (int u = 0; u < 2; ++u) {
    const int row = u * 32 + (tid >> 4), l16 = tid & 15;
    const int n = min(cnt[row], CAP);
    unsigned myk[CAP / 16];
    int rk[CAP / 16];
    #pragma unroll
    for (int j = 0; j < CAP / 16; ++j) {
      const int idx = l16 + 16 * j;
      myk[j] = (idx < n) ? keys2[row][idx] : 0u;
      rk[j] = 0;
    }
    for (int e = 0; e < n; ++e) {
      const unsigned k2 = keys2[row][e];
      #pragma unroll
      for (int j = 0; j < CAP / 16; ++j) rk[j] += (k2 > myk[j]) ? 1 : 0;
    }
    unsigned* gout = gkeys + (size_t)(mb + row) * MRG + hs * NS1;
    #pragma unroll
    for (int j = 0; j < CAP / 16; ++j) {
      const int idx = l16 + 16 * j;
      if (idx < n && rk[j] < NS1) gout[rk[j]] = myk[j];
    }
    // pads (statistically never taken): distinct idxparts mapping to h<0
    if (l16 == 0)
      for (int p = n; p < NS1; ++p) gout[p] = (unsigned)(0x4000 + hs * 64 + p);
  }
}

// ---------------- Kernel B2: merge halves + exact f64 rerank + decode ----
// (r4's proven fused kernel, 95us measured -- reverted from the r5 split)
__global__ __launch_bounds__(DT) void sae_dec(
    const float* __restrict__ x,    const float* __restrict__ Wenc,
    const float* __restrict__ benc, const float* __restrict__ Wdec,
    const float* __restrict__ bdec, const unsigned* __restrict__ gkeys,
    float* __restrict__ out)
{
  __shared__ unsigned mk[DBM][MRG];
  __shared__ __align__(16) float xf[DBM][XF_LD];
  __shared__ float tv[DBM][NS2];
  __shared__ int   ti[DBM][NS2];
  __shared__ float sv[DBM][TOPK];
  __shared__ int   si[DBM][TOPK];

  const int tid = (int)threadIdx.x;
  const int mb  = (int)blockIdx.x * DBM;

  #pragma unroll
  for (int i = tid; i < DBM * MRG; i += DT)
    mk[i / MRG][i % MRG] = gkeys[(size_t)mb * MRG + i];

  {  // stage exact f32 sae_in rows: 64 threads/row, 1 float4 each
    const int r = tid >> 6, seg = tid & 63;
    float4 xv = *(const float4*)(x + (size_t)(mb + r) * DIN + seg * 4);
    float4 bv = *(const float4*)(bdec + seg * 4);
    float4 d;
    d.x = xv.x - bv.x; d.y = xv.y - bv.y; d.z = xv.z - bv.z; d.w = xv.w - bv.w;
    *(float4*)&xf[r][seg * 4] = d;
  }
  __syncthreads();

  // merge: rank-select top-NS2 of 96 (keys unique); 16 lanes/row, 64 threads
  if (tid < DBM * 16) {
    const int row = tid >> 4, l16 = tid & 15;
    unsigned myk[6];
    int rk[6];
    #pragma unroll
    for (int j = 0; j < 6; ++j) {
      myk[j] = mk[row][l16 + 16 * j];
      rk[j]  = 0;
    }
    for (int e = 0; e < MRG; ++e) {
      unsigned k2 = mk[row][e];
      #pragma unroll
      for (int j = 0; j < 6; ++j) rk[j] += (k2 > myk[j]) ? 1 : 0;
    }
    #pragma unroll
    for (int j = 0; j < 6; ++j)
      if (rk[j] < NS2) ti[row][rk[j]] = 8191 - (int)(myk[j] & 0xFFFFu);
  }
  __syncthreads();

  // exact f64 rerank; 4 threads per (row,cand), 2 independent f64 chains
  {
    const int sub = tid & 3, pidx = tid >> 2;   // 64 pair-slots per pass
    #pragma unroll
    for (int j = 0; j < (DBM * NS2 * 4) / DT; ++j) {   // 3 passes
      const int pp = j * (DT / 4) + pidx;
      const int row = pp / NS2, cand = pp - row * NS2;
      const int h = ti[row][cand];
      double a0 = 0.0, a1 = 0.0;
      if (h >= 0) {    // pad guard (underfilled halves pad with h<0 keys)
        const float* wp = Wenc + (size_t)h * DIN + sub * 64;
        const float* xp = &xf[row][sub * 64];
        #pragma unroll
        for (int kk = 0; kk < 16; ++kk) {
          float4 w  = *(const float4*)(wp + 4 * kk);
          float4 xv = *(const float4*)(xp + 4 * kk);
          a0 += (double)xv.x * (double)w.x + (double)xv.y * (double)w.y;
          a1 += (double)xv.z * (double)w.z + (double)xv.w * (double)w.w;
        }
      }
      double accd = a0 + a1;
      accd += __shfl_down(accd, 2, 4);
      accd += __shfl_down(accd, 1, 4);
      if (sub == 0) {
        float ev = (h >= 0) ? ((float)accd + benc[h]) : 0.0f;
        ev = ev > 0.0f ? ev : 0.0f;   // relu before ranking (matches ref)
        tv[row][cand] = ev;
      }
    }
  }
  __syncthreads();

  // parallel exact top-32 rank-select (value desc, idx asc; ranks unique)
  if (tid < DBM * NS2) {
    const int row = tid / NS2, cand = tid - row * NS2;
    const float v = tv[row][cand];
    const int   h = ti[row][cand];
    int rk = 0;
    for (int e = 0; e < NS2; ++e) {
      const float v2 = tv[row][e];
      const int   h2 = ti[row][e];
      rk += (v2 > v || (v2 == v && (unsigned)h2 < (unsigned)h)) ? 1 : 0;
    }
    if (rk < TOPK) { sv[row][rk] = v; si[row][rk] = h; }
  }
  __syncthreads();

  // decode: out[b,:] = sum z_k * W_dec[idx_k,:] + b_dec; 64 threads/row
  {
    const int r = tid >> 6, d0 = (tid & 63) * 4;
    float4 bb = *(const float4*)(bdec + d0);
    float o0 = bb.x, o1 = bb.y, o2 = bb.z, o3 = bb.w;
    #pragma unroll
    for (int s = 0; s < TOPK; ++s) {
      const float v = sv[r][s];
      const int   h = si[r][s];
      const float* wp = Wdec + (size_t)((v > 0.0f) ? h : 0) * DIN + d0;
      float4 w = *(const float4*)wp;
      o0 += v * w.x; o1 += v * w.y; o2 += v * w.z; o3 += v * w.w;
    }
    float4 o;
    o.x = o0; o.y = o1; o.z = o2; o.w = o3;
    *(float4*)(out + (size_t)(mb + r) * DIN + d0) = o;
  }
}

extern "C" void kernel_launch(void* const* d_in, const int* in_sizes, int n_in,
                              void* d_out, int out_size, void* d_ws, size_t ws_size,
                              hipStream_t stream) {
  const float* x    = (const float*)d_in[0];
  const float* Wenc = (const float*)d_in[1];
  const float* benc = (const float*)d_in[2];
  const float* Wdec = (const float*)d_in[3];
  const float* bdec = (const float*)d_in[4];
  float* out = (float*)d_out;
  unsigned short* wsb = (unsigned short*)d_ws;                 // 4 MiB bf16 fragments
  unsigned* gkeys = (unsigned*)((char*)d_ws + GK_OFF);         // 3 MiB keys

  wenc_cast<<<dim3((HID * DIN / 8) / 512), dim3(512), 0, stream>>>(Wenc, wsb);
  sae_enc<<<dim3(2 * BATCH / BM), dim3(512), 0, stream>>>(x, benc, bdec, wsb, gkeys);
  sae_dec<<<dim3(BATCH / DBM), dim3(DT), 0, stream>>>(x, Wenc, benc, Wdec, bdec, gkeys, out);
}

// Round 7
// 242.085 us; speedup vs baseline: 1.1422x; 1.1137x over previous
//
#include <hip/hip_runtime.h>

#define DIN   256
#define HID   8192
#define BATCH 8192
#define TOPK  32
#define BM    64          // rows per sae_enc block
#define HHALF 4096
#define NCH   16          // hid chunks per half (256 latents each)
#define NS1   48          // per-half kept candidates (gkeys interface)
#define MRG   96          // merged candidates per row
#define NS2   48          // exact-rerank count
#define AS_LD 264         // 528 B row stride
#define XF_LD 260
#define CAP   112         // per-row spill cap (mean 57, 7.3 sigma)
#define K2_LD 113         // keys2 stride: odd => conflict-free row broadcast
#define WCAP  640         // per-wave spill list cap (mean 455, sd 21 -> 8.7 sigma)
#define THRM  0.1375f     // 2.2 / 16: threshold = 2.2 * (|x - b_dec| / sqrt(DIN))
#define DBM   4           // rows per sae_dec block
#define DT    256         // sae_dec threads
#define GK_OFF ((size_t)4 << 20)   // key buffer offset in ws (after 4MiB wsb)

typedef __bf16 bf16x8 __attribute__((ext_vector_type(8)));
typedef unsigned short u16x8 __attribute__((ext_vector_type(8)));
typedef float f32x4v __attribute__((ext_vector_type(4)));

__device__ __forceinline__ unsigned short f2bf(float f) {
  unsigned x = __builtin_bit_cast(unsigned, f);
  x = x + 0x7fffu + ((x >> 16) & 1u);   // RNE, finite only
  return (unsigned short)(x >> 16);
}

// ---------------- Kernel A: W_enc f32 -> bf16, MFMA-B-fragment layout ----
__global__ __launch_bounds__(512) void wenc_cast(
    const float* __restrict__ Wenc, unsigned short* __restrict__ wsb)
{
  const int g = (int)blockIdx.x * 512 + (int)threadIdx.x;  // 262144 units
  const int h = g >> 5, u = g & 31, kg = u >> 2, quad = u & 3;
  const float* src = Wenc + (size_t)h * DIN + kg * 32 + quad * 8;
  float4 a = *(const float4*)src;
  float4 b = *(const float4*)(src + 4);
  u16x8 o;
  o[0] = f2bf(a.x); o[1] = f2bf(a.y); o[2] = f2bf(a.z); o[3] = f2bf(a.w);
  o[4] = f2bf(b.x); o[5] = f2bf(b.y); o[6] = f2bf(b.z); o[7] = f2bf(b.w);
  *(u16x8*)(wsb + ((size_t)(((h >> 4) * 8 + kg) * 64 + quad * 16 + (h & 15))) * 8) = o;
}

// ---------------- Kernel B1: encoder GEMM + ballot-batched spill + top-48 ----
// r5 skeleton (BM=64 x 8 waves, grid 256, afrag[4][8] in regs, direct L2
// bfrag loads). The r2/r5/r6 enc kernels were ALL bound by the spill
// epilogue: 16 sequential divergent ds_add_rtn blocks ~ 2.4Kcy/tile.
// Replaced with an atomic-FREE wave-local append: __ballot per slot, lane
// offset = popc(mask below lane), list length = wave-uniform register.
// Per-wave (key,row) lists overlay the dead As tile; a post-loop bucketize
// (distributed LDS atomics) rebuilds keys2, then the proven rank-select.
__global__ __launch_bounds__(512) void sae_enc(
    const float* __restrict__ x,    const float* __restrict__ benc,
    const float* __restrict__ bdec, const unsigned short* __restrict__ wsb,
    unsigned* __restrict__ gkeys)
{
  __shared__ __align__(16) union UA {
    unsigned short As[BM][AS_LD];                                  // 33.8 KB
    struct { unsigned wkey[8][WCAP]; unsigned char wrow[8][WCAP]; } w;  // 25.6 KB
  } ua;
  __shared__ unsigned keys2[BM][K2_LD];                            // 28.9 KB
  __shared__ int   cnt[BM];
  __shared__ float rthr[BM];
  __shared__ int   wn[8];

  const int tid  = (int)threadIdx.x;
  const int wave = tid >> 6;
  const int lane = tid & 63;
  const int quad = lane >> 4;
  const int ln15 = lane & 15;
  const int rt   = (int)blockIdx.x >> 1;
  const int hs   = (int)blockIdx.x & 1;
  const int mb   = rt * BM;

  // ---- stage bf16(x - b_dec) rows into LDS.As + per-row threshold ----
  #pragma unroll
  for (int u = 0; u < 2; ++u) {
    const int idx = u * 512 + tid;
    const int r = idx >> 4, seg = idx & 15;
    const float* xs = x + (size_t)(mb + r) * DIN + seg * 16;
    const float* bs = bdec + seg * 16;
    float ss = 0.0f;
    #pragma unroll
    for (int j = 0; j < 4; ++j) {
      float4 xv = *(const float4*)(xs + 4 * j);
      float4 bv = *(const float4*)(bs + 4 * j);
      float dx = xv.x - bv.x, dy = xv.y - bv.y;
      float dz = xv.z - bv.z, dw = xv.w - bv.w;
      ss += dx * dx + dy * dy + dz * dz + dw * dw;
      unsigned short* dst = &ua.As[r][seg * 16 + 4 * j];
      dst[0] = f2bf(dx); dst[1] = f2bf(dy);
      dst[2] = f2bf(dz); dst[3] = f2bf(dw);
    }
    #pragma unroll
    for (int d = 1; d < 16; d <<= 1) ss += __shfl_xor(ss, d, 16);
    if (seg == 0) { rthr[r] = THRM * sqrtf(ss); cnt[r] = 0; }
  }
  __syncthreads();

  // A-fragments in registers (verified 16x16x32 layout): A[m][k=quad*8+j]
  bf16x8 afrag[4][8];
  #pragma unroll
  for (int mt = 0; mt < 4; ++mt)
    #pragma unroll
    for (int gk = 0; gk < 8; ++gk)
      afrag[mt][gk] = *(const bf16x8*)&ua.As[mt * 16 + ln15][gk * 32 + quad * 8];

  float thr[16];
  #pragma unroll
  for (int s = 0; s < 16; ++s) thr[s] = rthr[(s >> 2) * 16 + quad * 4 + (s & 3)];
  __syncthreads();   // As fully consumed before the wave lists overlay it

  unsigned wbase = 0;   // my wave's list length (uniform across lanes)

  for (int c = 0; c < NCH; ++c) {
    const unsigned short* bp =
        wsb + (((size_t)(hs * 256 + c * 16 + wave * 2) * 512) + lane) * 8;
    #pragma unroll
    for (int nt = 0; nt < 2; ++nt) {
      bf16x8 bfrag[8];
      #pragma unroll
      for (int kg = 0; kg < 8; ++kg)
        bfrag[kg] = *(const bf16x8*)(bp + (size_t)nt * 4096 + (size_t)kg * 512);

      const int hcol = hs * HHALF + c * 256 + (wave * 2 + nt) * 16 + ln15;
      const float be = benc[hcol];
      f32x4v acc[4];
      #pragma unroll
      for (int mt = 0; mt < 4; ++mt)
        #pragma unroll
        for (int i = 0; i < 4; ++i) acc[mt][i] = be;   // b_enc folded into init

      #pragma unroll
      for (int kg = 0; kg < 8; ++kg)
        #pragma unroll
        for (int mt = 0; mt < 4; ++mt)
          acc[mt] = __builtin_amdgcn_mfma_f32_16x16x32_bf16(
              afrag[mt][kg], bfrag[kg], acc[mt], 0, 0, 0);

      // ballot-batched spill: no atomics, fire-and-forget ds_writes
      const unsigned idxpart = (unsigned)(8191 - hcol);
      #pragma unroll
      for (int s = 0; s < 16; ++s) {
        const int mt = s >> 2, i = s & 3;
        const bool take = acc[mt][i] > thr[s];   // thr>0 => take implies relu=v
        const unsigned long long bm = __ballot(take);
        if (take) {
          const int pos = (int)wbase + __popcll(bm & ((1ull << lane) - 1ull));
          if (pos < WCAP) {
            ua.w.wkey[wave][pos] = ((unsigned)f2bf(acc[mt][i]) << 16) | idxpart;
            ua.w.wrow[wave][pos] = (unsigned char)(mt * 16 + quad * 4 + i);
          }
        }
        wbase += (unsigned)__popcll(bm);
      }
    }
  }
  if (lane == 0) wn[wave] = (int)(wbase < WCAP ? wbase : WCAP);
  __syncthreads();

  // bucketize wave lists into per-row lists (distributed LDS atomics)
  for (int w = 0; w < 8; ++w) {
    const int n = wn[w];
    for (int e = tid; e < n; e += 512) {
      const unsigned k = ua.w.wkey[w][e];
      const int row = (int)ua.w.wrow[w][e];
      const int sl = atomicAdd(&cnt[row], 1);
      if (sl < CAP) keys2[row][sl] = k;
    }
  }
  __syncthreads();

  // rank-select top-NS1 per row (keys unique) -> global key buffer
  #pragma unroll
  for (int u = 0; u < 2; ++u) {
    const int row = u * 32 + (tid >> 4), l16 = tid & 15;
    const int n = min(cnt[row], CAP);
    unsigned myk[CAP / 16];
    int rk[CAP / 16];
    #pragma unroll
    for (int j = 0; j < CAP / 16; ++j) {
      const int idx = l16 + 16 * j;
      myk[j] = (idx < n) ? keys2[row][idx] : 0u;
      rk[j] = 0;
    }
    for (int e = 0; e < n; ++e) {
      const unsigned k2 = keys2[row][e];
      #pragma unroll
      for (int j = 0; j < CAP / 16; ++j) rk[j] += (k2 > myk[j]) ? 1 : 0;
    }
    unsigned* gout = gkeys + (size_t)(mb + row) * MRG + hs * NS1;
    #pragma unroll
    for (int j = 0; j < CAP / 16; ++j) {
      const int idx = l16 + 16 * j;
      if (idx < n && rk[j] < NS1) gout[rk[j]] = myk[j];
    }
    // pads (statistically never taken): distinct idxparts mapping to h<0
    if (l16 == 0)
      for (int p = n; p < NS1; ++p) gout[p] = (unsigned)(0x4000 + hs * 64 + p);
  }
}

// ---------------- Kernel B2: merge halves + exact f64 rerank + decode ----
// (r4's proven fused kernel -- unchanged for a clean A/B on sae_enc)
__global__ __launch_bounds__(DT) void sae_dec(
    const float* __restrict__ x,    const float* __restrict__ Wenc,
    const float* __restrict__ benc, const float* __restrict__ Wdec,
    const float* __restrict__ bdec, const unsigned* __restrict__ gkeys,
    float* __restrict__ out)
{
  __shared__ unsigned mk[DBM][MRG];
  __shared__ __align__(16) float xf[DBM][XF_LD];
  __shared__ float tv[DBM][NS2];
  __shared__ int   ti[DBM][NS2];
  __shared__ float sv[DBM][TOPK];
  __shared__ int   si[DBM][TOPK];

  const int tid = (int)threadIdx.x;
  const int mb  = (int)blockIdx.x * DBM;

  #pragma unroll
  for (int i = tid; i < DBM * MRG; i += DT)
    mk[i / MRG][i % MRG] = gkeys[(size_t)mb * MRG + i];

  {  // stage exact f32 sae_in rows: 64 threads/row, 1 float4 each
    const int r = tid >> 6, seg = tid & 63;
    float4 xv = *(const float4*)(x + (size_t)(mb + r) * DIN + seg * 4);
    float4 bv = *(const float4*)(bdec + seg * 4);
    float4 d;
    d.x = xv.x - bv.x; d.y = xv.y - bv.y; d.z = xv.z - bv.z; d.w = xv.w - bv.w;
    *(float4*)&xf[r][seg * 4] = d;
  }
  __syncthreads();

  // merge: rank-select top-NS2 of 96 (keys unique); 16 lanes/row, 64 threads
  if (tid < DBM * 16) {
    const int row = tid >> 4, l16 = tid & 15;
    unsigned myk[6];
    int rk[6];
    #pragma unroll
    for (int j = 0; j < 6; ++j) {
      myk[j] = mk[row][l16 + 16 * j];
      rk[j]  = 0;
    }
    for (int e = 0; e < MRG; ++e) {
      unsigned k2 = mk[row][e];
      #pragma unroll
      for (int j = 0; j < 6; ++j) rk[j] += (k2 > myk[j]) ? 1 : 0;
    }
    #pragma unroll
    for (int j = 0; j < 6; ++j)
      if (rk[j] < NS2) ti[row][rk[j]] = 8191 - (int)(myk[j] & 0xFFFFu);
  }
  __syncthreads();

  // exact f64 rerank; 4 threads per (row,cand), 2 independent f64 chains
  {
    const int sub = tid & 3, pidx = tid >> 2;   // 64 pair-slots per pass
    #pragma unroll
    for (int j = 0; j < (DBM * NS2 * 4) / DT; ++j) {   // 3 passes
      const int pp = j * (DT / 4) + pidx;
      const int row = pp / NS2, cand = pp - row * NS2;
      const int h = ti[row][cand];
      double a0 = 0.0, a1 = 0.0;
      if (h >= 0) {    // pad guard (underfilled halves pad with h<0 keys)
        const float* wp = Wenc + (size_t)h * DIN + sub * 64;
        const float* xp = &xf[row][sub * 64];
        #pragma unroll
        for (int kk = 0; kk < 16; ++kk) {
          float4 w  = *(const float4*)(wp + 4 * kk);
          float4 xv = *(const float4*)(xp + 4 * kk);
          a0 += (double)xv.x * (double)w.x + (double)xv.y * (double)w.y;
          a1 += (double)xv.z * (double)w.z + (double)xv.w * (double)w.w;
        }
      }
      double accd = a0 + a1;
      accd += __shfl_down(accd, 2, 4);
      accd += __shfl_down(accd, 1, 4);
      if (sub == 0) {
        float ev = (h >= 0) ? ((float)accd + benc[h]) : 0.0f;
        ev = ev > 0.0f ? ev : 0.0f;   // relu before ranking (matches ref)
        tv[row][cand] = ev;
      }
    }
  }
  __syncthreads();

  // parallel exact top-32 rank-select (value desc, idx asc; ranks unique)
  if (tid < DBM * NS2) {
    const int row = tid / NS2, cand = tid - row * NS2;
    const float v = tv[row][cand];
    const int   h = ti[row][cand];
    int rk = 0;
    for (int e = 0; e < NS2; ++e) {
      const float v2 = tv[row][e];
      const int   h2 = ti[row][e];
      rk += (v2 > v || (v2 == v && (unsigned)h2 < (unsigned)h)) ? 1 : 0;
    }
    if (rk < TOPK) { sv[row][rk] = v; si[row][rk] = h; }
  }
  __syncthreads();

  // decode: out[b,:] = sum z_k * W_dec[idx_k,:] + b_dec; 64 threads/row
  {
    const int r = tid >> 6, d0 = (tid & 63) * 4;
    float4 bb = *(const float4*)(bdec + d0);
    float o0 = bb.x, o1 = bb.y, o2 = bb.z, o3 = bb.w;
    #pragma unroll
    for (int s = 0; s < TOPK; ++s) {
      const float v = sv[r][s];
      const int   h = si[r][s];
      const float* wp = Wdec + (size_t)((v > 0.0f) ? h : 0) * DIN + d0;
      float4 w = *(const float4*)wp;
      o0 += v * w.x; o1 += v * w.y; o2 += v * w.z; o3 += v * w.w;
    }
    float4 o;
    o.x = o0; o.y = o1; o.z = o2; o.w = o3;
    *(float4*)(out + (size_t)(mb + r) * DIN + d0) = o;
  }
}

extern "C" void kernel_launch(void* const* d_in, const int* in_sizes, int n_in,
                              void* d_out, int out_size, void* d_ws, size_t ws_size,
                              hipStream_t stream) {
  const float* x    = (const float*)d_in[0];
  const float* Wenc = (const float*)d_in[1];
  const float* benc = (const float*)d_in[2];
  const float* Wdec = (const float*)d_in[3];
  const float* bdec = (const float*)d_in[4];
  float* out = (float*)d_out;
  unsigned short* wsb = (unsigned short*)d_ws;                 // 4 MiB bf16 fragments
  unsigned* gkeys = (unsigned*)((char*)d_ws + GK_OFF);         // 3 MiB keys

  wenc_cast<<<dim3((HID * DIN / 8) / 512), dim3(512), 0, stream>>>(Wenc, wsb);
  sae_enc<<<dim3(2 * BATCH / BM), dim3(512), 0, stream>>>(x, benc, bdec, wsb, gkeys);
  sae_dec<<<dim3(BATCH / DBM), dim3(DT), 0, stream>>>(x, Wenc, benc, Wdec, bdec, gkeys, out);
}